// Round 6
// baseline (579.233 us; speedup 1.0000x reference)
//
#include <hip/hip_runtime.h>

#define S_LEN 2048
#define NHEAD 16

typedef float f32x4 __attribute__((ext_vector_type(4)));
typedef __bf16 bf16x8 __attribute__((ext_vector_type(8)));
typedef __bf16 bf16x4 __attribute__((ext_vector_type(4)));

#define AS1 __attribute__((address_space(1)))
#define AS3 __attribute__((address_space(3)))

// async 16B/lane global->LDS; lds base wave-uniform (dest = base + lane*16)
__device__ __forceinline__ void gl2lds16(const void* g, void* l) {
    __builtin_amdgcn_global_load_lds((const AS1 unsigned int*)g,
                                     (AS3 unsigned int*)l, 16, 0, 0);
}
// barrier leaving newest N vmem loads in flight (proj kernel)
__device__ __forceinline__ void wb_leave4() {
    asm volatile("s_waitcnt vmcnt(4)\n\ts_barrier" ::: "memory");
}
__device__ __forceinline__ void wb_drain() {
    asm volatile("s_waitcnt vmcnt(0)\n\ts_barrier" ::: "memory");
}

// ---------------- cast+swizzle A: q,k,v fp32[8192][1024] -> bf16, 16B chunks
// within each 64-elem k-segment permuted by (chunk ^ row&7) -------------------
__global__ __launch_bounds__(256) void cast_swizzle_kernel(
    const float* __restrict__ q, const float* __restrict__ k,
    const float* __restrict__ v, __bf16* __restrict__ out)
{
    int gid = blockIdx.x * 256 + threadIdx.x;
    int z   = gid >> 20;
    int rem = gid & 1048575;
    int r   = rem >> 7;
    int c   = rem & 127;
    const float* src = (z == 0 ? q : z == 1 ? k : v) + (size_t)r * 1024 + c * 8;
    float4 a = *(const float4*)src;
    float4 b = *(const float4*)(src + 4);
    bf16x8 t;
    t[0] = (__bf16)a.x; t[1] = (__bf16)a.y; t[2] = (__bf16)a.z; t[3] = (__bf16)a.w;
    t[4] = (__bf16)b.x; t[5] = (__bf16)b.y; t[6] = (__bf16)b.z; t[7] = (__bf16)b.w;
    int cp = (c & ~7) | ((c ^ r) & 7);
    *(bf16x8*)(out + (size_t)z * 8388608 + (size_t)r * 1024 + cp * 8) = t;
}

// ---------------- W transpose+cast+swizzle: W[k][n] f32 -> Wt[n][k] bf16 -----
__global__ __launch_bounds__(256) void transpose_cast_kernel(
    const float* __restrict__ W0, const float* __restrict__ W1,
    const float* __restrict__ W2, __bf16* __restrict__ Wt)
{
    int z = blockIdx.z;
    const float* W = (z == 0 ? W0 : z == 1 ? W1 : W2);
    __bf16* out = Wt + (size_t)z * 1048576;
    __shared__ float tile[32][33];
    int bx = blockIdx.x, by = blockIdx.y;
    int tid = threadIdx.x;
    int tx = tid & 31, ty = tid >> 5;
    for (int i = 0; i < 32; i += 8)
        tile[ty + i][tx] = W[(size_t)(by * 32 + ty + i) * 1024 + bx * 32 + tx];
    __syncthreads();
    if (tid < 128) {
        int nl = tid >> 2, kc = tid & 3;
        int n = bx * 32 + nl;
        int kbase = by * 32 + kc * 8;
        bf16x8 t;
        for (int j = 0; j < 8; j++) t[j] = (__bf16)tile[kc * 8 + j][nl];
        int cp = ((kbase >> 3) ^ n) & 7;
        *(bf16x8*)(out + (size_t)n * 1024 + (kbase & ~63) + cp * 8) = t;
    }
}

// ---------------- fused projection GEMM (z = 0:Q, 1:K, 2:V) ------------------
__global__ __launch_bounds__(256, 3) void proj_gemm_kernel(
    const __bf16* __restrict__ Abf, const __bf16* __restrict__ Wt,
    __bf16* __restrict__ qw, __bf16* __restrict__ kw, __bf16* __restrict__ vt)
{
    int z = blockIdx.z;
    const __bf16* A = Abf + (size_t)z * 8388608;
    const __bf16* B = Wt + (size_t)z * 1048576;
    __shared__ __align__(16) char smem[49152];

    int tid = threadIdx.x;
    int bm = blockIdx.x, bn = blockIdx.y;
    int wave = tid >> 6, lane = tid & 63;
    int wm = (wave >> 1) * 64, wn = (wave & 1) * 64;
    int lrow = lane & 15;
    int q4 = lane >> 4;
    int l4r = lane >> 2, j4 = lane & 3;

    auto pf = [&](int kb) {
        int sl = kb % 3;
        int k0 = kb * 32;
        int segbyte = (k0 >> 6) * 128;
        int cbase = (k0 & 32) >> 3;
        for (int i = 0; i < 2; i++) {
            int r = wave * 32 + i * 16 + l4r;
            int cl = j4 ^ ((r >> 1) & 3);
            int phys = ((cbase + cl) ^ r) & 7;
            gl2lds16((const char*)A + (size_t)(bm * 128 + r) * 2048 + segbyte + phys * 16,
                     smem + sl * 8192 + wave * 2048 + i * 1024);
            gl2lds16((const char*)B + (size_t)(bn * 128 + r) * 2048 + segbyte + phys * 16,
                     smem + 24576 + sl * 8192 + wave * 2048 + i * 1024);
        }
    };

    f32x4 zero = {0.f, 0.f, 0.f, 0.f};
    f32x4 acc[4][4];
    for (int mt = 0; mt < 4; mt++)
        for (int nt = 0; nt < 4; nt++) acc[mt][nt] = zero;

    pf(0); pf(1);
    __syncthreads();
    for (int kb = 0; kb < 32; kb++) {
        if (kb == 31) wb_drain(); else wb_leave4();
        if (kb + 2 < 32) pf(kb + 2);
        int sA = (kb % 3) * 8192, sB = 24576 + (kb % 3) * 8192;
        bf16x8 af[4], bfv[4];
        for (int mt = 0; mt < 4; mt++) {
            int r = wm + mt * 16 + lrow;
            af[mt] = *(const bf16x8*)(smem + sA + r * 64 + (q4 ^ ((r >> 1) & 3)) * 16);
        }
        for (int nt = 0; nt < 4; nt++) {
            int r = wn + nt * 16 + lrow;
            bfv[nt] = *(const bf16x8*)(smem + sB + r * 64 + (q4 ^ ((r >> 1) & 3)) * 16);
        }
        for (int mt = 0; mt < 4; mt++)
            for (int nt = 0; nt < 4; nt++)
                acc[mt][nt] = __builtin_amdgcn_mfma_f32_16x16x32_bf16(
                    af[mt], bfv[nt], acc[mt][nt], 0, 0, 0);
    }
    __syncthreads();
    __bf16* T = (__bf16*)smem;     // row stride 136 elems (272 B)

    float oscale = (z == 0) ? 0.125f : 1.0f;
    int rowoff = q4 * 4;
    int b = bm >> 4;
    int s_base = (bm & 15) * 128;
    if (z < 2) {
        for (int mt = 0; mt < 4; mt++) {
            for (int nt = 0; nt < 4; nt++) {
                int n_local = wn + nt * 16 + lrow;
                int hl = n_local >> 6, d = n_local & 63;
                for (int reg = 0; reg < 4; reg++) {
                    int s_local = wm + mt * 16 + rowoff + reg;
                    int s = s_base + s_local;
                    int dp = (d & 7) | ((((d >> 3) ^ s) & 7) << 3);
                    T[s_local * 136 + hl * 64 + dp] = (__bf16)(acc[mt][nt][reg] * oscale);
                }
            }
        }
        __syncthreads();
        char* gq = (char*)(z == 0 ? qw : kw);
        for (int i = 0; i < 8; i++) {
            int id = tid + i * 256;
            int hl = id >> 10, r = (id >> 3) & 127, j = id & 7;
            float4 val = *(float4*)((char*)T + r * 272 + hl * 128 + j * 16);
            *(float4*)(gq + ((size_t)((b * 16 + bn * 2 + hl) * 2048) + s_base + r) * 128
                          + j * 16) = val;
        }
    } else {
        for (int mt = 0; mt < 4; mt++) {
            int s0 = wm + mt * 16 + rowoff;
            int seg = s0 >> 6, j0 = s0 & 63;
            for (int nt = 0; nt < 4; nt++) {
                int n_local = wn + nt * 16 + lrow;
                int d = n_local & 63;
                int hi = ((j0 >> 3) ^ d) & 7;
                bf16x4 pk;
                for (int reg = 0; reg < 4; reg++) pk[reg] = (__bf16)acc[mt][nt][reg];
                *(bf16x4*)&T[n_local * 136 + seg * 64 + hi * 8 + (j0 & 7)] = pk;
            }
        }
        __syncthreads();
        char* gv = (char*)vt;
        for (int i = 0; i < 8; i++) {
            int id = tid + i * 256;
            int nl = id >> 4, j = id & 15;
            int hl = nl >> 6, dv = nl & 63;
            float4 val = *(float4*)((char*)T + nl * 272 + j * 16);
            *(float4*)(gv + (((size_t)((b * 16 + bn * 2 + hl) * 64 + dv)) * 2048 + s_base) * 2
                          + j * 16) = val;
        }
    }
}

// ---------------- flash attention, round 6: ABLATION PROBE -------------------
// Five rounds of structural fixes (occupancy, L2 locality, balance, LDS
// staging, barrier drain) all landed at 106-108us with every pipe <35% busy.
// Theory-first has failed 4x; this round measures where the time actually is
// (m164-m166 pattern). template<ABL> variants each remove ONE phase; all are
// launched (garbage into out), real variant <0> runs LAST and overwrites
// everything (grid covers all rows), so correctness is preserved.
//   ABL=1: no softmax exp/penalty/causal  (pv = raw sacc)
//   ABL=2: no P LDS round-trip            (PV A-operand = qfr)
//   ABL=3: no V reads / PV MFMA           (o_acc += sacc keeps chain live)
//   ABL=4: no K reads / QK MFMA           (sacc = const)
//   ABL=5: no K/V staging, no vmcnt waits (reads stale LDS)
// DCE guard (rule 17): every skipped phase's inputs still flow into lt /
// o_acc / the store, so upstream work isn't deleted.
template <int ABL>
__global__ __launch_bounds__(256, 2) void attn_kernel(
    const __bf16* __restrict__ QW, const __bf16* __restrict__ KW,
    const __bf16* __restrict__ VT, const float* __restrict__ v_mask,
    const float* __restrict__ q_mask, float* __restrict__ out)
{
    int lin = blockIdx.x + (blockIdx.y << 4);
    int xcd = lin & 7;
    int jj  = lin >> 3;
    int bh  = (xcd << 3) + (jj >> 4);
    int bx  = jj & 15;
    int b = bh >> 4, h = bh & 15;

    __shared__ __align__(16) char lds[40960];
    char* Kb0 = lds;            // [2][8192] K tiles (64 keys x 128B, swizzled)
    char* Vb0 = lds + 16384;    // [2][8192] V tiles (64 dv x 128B, swizzled)
    char* Pw  = lds + 32768;    // 4 waves x 2KB P (16 q x 128B, swizzled)

    int tid = threadIdx.x;
    int wave = tid >> 6, lane = tid & 63;
    int mloc = lane & 15, q4 = lane >> 4;
    int rowoff = q4 * 4, x7 = mloc & 7;
    char* Pme = Pw + wave * 2048;

    const char* Krow = (const char*)KW + (size_t)bh * 2048 * 128;
    const char* Vrow = (const char*)VT + (size_t)bh * 64 * 4096;
    const float* vmrow = v_mask + (size_t)b * 2048;

    int id0 = tid, id1 = tid + 256;

    auto stage = [&](int kb, int slot) {
        char* kd = Kb0 + slot * 8192;
        char* vd = Vb0 + slot * 8192;
        gl2lds16(Krow + (size_t)(kb * 64 + (id0 >> 3)) * 128 + (id0 & 7) * 16,
                 kd + id0 * 16);
        gl2lds16(Krow + (size_t)(kb * 64 + (id1 >> 3)) * 128 + (id1 & 7) * 16,
                 kd + id1 * 16);
        gl2lds16(Vrow + (size_t)(id0 >> 3) * 4096 + (size_t)kb * 128 + (id0 & 7) * 16,
                 vd + id0 * 16);
        gl2lds16(Vrow + (size_t)(id1 >> 3) * 4096 + (size_t)kb * 128 + (id1 & 7) * 16,
                 vd + id1 * 16);
    };

    f32x4 zero = {0.f, 0.f, 0.f, 0.f};

    for (int p = 0; p < 2; p++) {
        int qb = p ? (31 - bx) : bx;
        const char* Qrow = (const char*)QW +
                           ((size_t)bh * 2048 + qb * 64 + wave * 16) * 128;
        bf16x8 qfr[2];
        for (int kc = 0; kc < 2; kc++)
            qfr[kc] = *(const bf16x8*)(Qrow + mloc * 128 + (((kc * 4 + q4) ^ x7) << 4));

        if constexpr (ABL != 5) stage(0, 0);
        float4 vm4[4];
        for (int m = 0; m < 4; m++)
            vm4[m] = *(const float4*)(vmrow + m * 16 + rowoff);

        f32x4 o_acc[4];
        for (int nt = 0; nt < 4; nt++) o_acc[nt] = zero;
        float lt = 0.f;

        for (int kb = 0; kb <= qb; kb++) {
            int slot = kb & 1;
            if constexpr (ABL != 5) {
                if (kb < qb) {
                    stage(kb + 1, slot ^ 1);
                    asm volatile("s_waitcnt vmcnt(8)\n\ts_barrier" ::: "memory");
                } else {
                    asm volatile("s_waitcnt vmcnt(4)\n\ts_barrier" ::: "memory");
                }
            } else {
                if (kb < qb) { /* nothing staged */ }
                asm volatile("s_barrier" ::: "memory");
            }
            const char* Kls = Kb0 + slot * 8192;
            const char* Vls = Vb0 + slot * 8192;

            // ---- QK^T ----
            f32x4 sacc[4];
            if constexpr (ABL != 4) {
                for (int m = 0; m < 4; m++) sacc[m] = zero;
                for (int kc = 0; kc < 2; kc++) {
                    bf16x8 kfr[4];
                    for (int m = 0; m < 4; m++)
                        kfr[m] = *(const bf16x8*)(Kls + (m * 16 + mloc) * 128 +
                                                  (((kc * 4 + q4) ^ x7) << 4));
                    for (int m = 0; m < 4; m++)
                        sacc[m] = __builtin_amdgcn_mfma_f32_16x16x32_bf16(
                            kfr[m], qfr[kc], sacc[m], 0, 0, 0);
                }
            } else {
                for (int m = 0; m < 4; m++) {
                    f32x4 c = {0.5f, -0.25f, 0.125f, -0.5f};
                    sacc[m] = c;
                }
            }

            // ---- softmax numerator + P pack ----
            for (int m = 0; m < 4; m++) {
                float pv[4];
                if constexpr (ABL != 1) {
                    float pen[4];
                    pen[0] = fmaf(1.0f - vm4[m].x, 1.0e9f, 12.0f);
                    pen[1] = fmaf(1.0f - vm4[m].y, 1.0e9f, 12.0f);
                    pen[2] = fmaf(1.0f - vm4[m].z, 1.0e9f, 12.0f);
                    pen[3] = fmaf(1.0f - vm4[m].w, 1.0e9f, 12.0f);
                    for (int reg = 0; reg < 4; reg++)
                        pv[reg] = __expf(sacc[m][reg] - pen[reg]);
                    if (kb == qb)
                        for (int reg = 0; reg < 4; reg++)
                            if (m * 16 + rowoff + reg > wave * 16 + mloc) pv[reg] = 0.f;
                } else {
                    for (int reg = 0; reg < 4; reg++) pv[reg] = sacc[m][reg];
                }
                lt += (pv[0] + pv[1]) + (pv[2] + pv[3]);
                if constexpr (ABL != 2) {
                    bf16x4 pk;
                    for (int reg = 0; reg < 4; reg++) pk[reg] = (__bf16)pv[reg];
                    *(bf16x4*)(Pme + mloc * 128 +
                               (((m * 2 + (q4 >> 1)) ^ x7) << 4) + (q4 & 1) * 8) = pk;
                }
            }
            // prefetch next tile's v_mask
            if (kb < qb)
                for (int m = 0; m < 4; m++)
                    vm4[m] = *(const float4*)(vmrow + (kb + 1) * 64 + m * 16 + rowoff);

            // ---- PV ----
            if constexpr (ABL != 3) {
                for (int kc = 0; kc < 2; kc++) {
                    bf16x8 afr;
                    if constexpr (ABL != 2)
                        afr = *(const bf16x8*)(Pme + mloc * 128 +
                                               (((kc * 4 + q4) ^ x7) << 4));
                    else
                        afr = qfr[kc];   // no P round-trip: reg-available A
                    bf16x8 vfr[4];
                    for (int nt = 0; nt < 4; nt++)
                        vfr[nt] = *(const bf16x8*)(Vls + (nt * 16 + mloc) * 128 +
                                                   (((kc * 4 + q4) ^ x7) << 4));
                    for (int nt = 0; nt < 4; nt++)
                        o_acc[nt] = __builtin_amdgcn_mfma_f32_16x16x32_bf16(
                            afr, vfr[nt], o_acc[nt], 0, 0, 0);
                }
            } else {
                for (int nt = 0; nt < 4; nt++) o_acc[nt] += sacc[nt];
            }
            asm volatile("s_barrier" ::: "memory");
        }

        lt += __shfl_xor(lt, 16);
        lt += __shfl_xor(lt, 32);

        if constexpr (ABL == 0) {
            // degenerate queries: uniform softmax over {window} U {unmasked
            // future}. Wave-local indicator pass, V from global (rare).
            if (__any(lt == 0.0f)) {
                float l2 = 0.f;
                bool degrow = (lt == 0.0f);
                int qrow = qb * 64 + wave * 16 + mloc;
                for (int kb2 = 0; kb2 < 32; kb2++) {
                    bf16x8 vfr[4][2];
                    for (int nt = 0; nt < 4; nt++)
                        for (int kc = 0; kc < 2; kc++)
                            vfr[nt][kc] = *(const bf16x8*)(Vrow +
                                (size_t)(nt * 16 + mloc) * 4096 +
                                kb2 * 128 + (((kc * 4 + q4) ^ x7) << 4));
                    for (int kc = 0; kc < 2; kc++) {
                        const float* vmp = vmrow + kb2 * 64 + kc * 32 + q4 * 8;
                        float4 va = *(const float4*)vmp;
                        float4 vb4 = *(const float4*)(vmp + 4);
                        float vmj[8] = {va.x, va.y, va.z, va.w,
                                        vb4.x, vb4.y, vb4.z, vb4.w};
                        int kg0 = kb2 * 64 + kc * 32 + q4 * 8;
                        bf16x8 af;
                        float cnt = 0.f;
                        for (int j = 0; j < 8; j++) {
                            float ind = degrow ? ((kg0 + j <= qrow) ? 1.0f : vmj[j]) : 0.0f;
                            af[j] = (__bf16)ind;
                            cnt += ind;
                        }
                        l2 += cnt;
                        for (int nt = 0; nt < 4; nt++)
                            o_acc[nt] = __builtin_amdgcn_mfma_f32_16x16x32_bf16(
                                af, vfr[nt][kc], o_acc[nt], 0, 0, 0);
                    }
                }
                l2 += __shfl_xor(l2, 16);
                l2 += __shfl_xor(l2, 32);
                if (degrow) lt = l2;
            }
        }

        // epilogue: direct scaled store
        float sc[4];
        for (int reg = 0; reg < 4; reg++) {
            float lq = __shfl(lt, rowoff + reg);
            sc[reg] = q_mask[b * 2048 + qb * 64 + wave * 16 + rowoff + reg] / lq;
        }
        for (int nt = 0; nt < 4; nt++)
            for (int reg = 0; reg < 4; reg++)
                out[((size_t)(b * 2048 + qb * 64 + wave * 16 + rowoff + reg)) * 1024 +
                    h * 64 + nt * 16 + mloc] = o_acc[nt][reg] * sc[reg];
    }
}

// ---------------- launch ------------------------------------------------------
extern "C" void kernel_launch(void* const* d_in, const int* in_sizes, int n_in,
                              void* d_out, int out_size, void* d_ws, size_t ws_size,
                              hipStream_t stream)
{
    const float* q      = (const float*)d_in[0];
    const float* k      = (const float*)d_in[1];
    const float* v      = (const float*)d_in[2];
    const float* v_mask = (const float*)d_in[3];
    const float* q_mask = (const float*)d_in[4];
    const float* Wq     = (const float*)d_in[5];
    const float* Wk     = (const float*)d_in[6];
    const float* Wv     = (const float*)d_in[7];
    float* out = (float*)d_out;

    __bf16* Abf = (__bf16*)d_ws;                 // 3 x 8192 x 1024
    __bf16* Wt  = Abf + (size_t)3 * 8388608;     // 3 x 1024 x 1024
    __bf16* qw  = Wt + (size_t)3 * 1048576;      // [B*H][S][64] (x0.125)
    __bf16* kw  = qw + (size_t)8388608;
    __bf16* vt  = kw + (size_t)8388608;          // [B*H][64][S]

    cast_swizzle_kernel<<<12288, 256, 0, stream>>>(q, k, v, Abf);
    transpose_cast_kernel<<<dim3(32, 32, 3), 256, 0, stream>>>(Wq, Wk, Wv, Wt);
    proj_gemm_kernel<<<dim3(64, 8, 3), 256, 0, stream>>>(Abf, Wt, qw, kw, vt);

    // ablation probes (garbage output, overwritten by the real kernel below)
    attn_kernel<1><<<dim3(16, 64), 256, 0, stream>>>(qw, kw, vt, v_mask, q_mask, out);
    attn_kernel<2><<<dim3(16, 64), 256, 0, stream>>>(qw, kw, vt, v_mask, q_mask, out);
    attn_kernel<3><<<dim3(16, 64), 256, 0, stream>>>(qw, kw, vt, v_mask, q_mask, out);
    attn_kernel<4><<<dim3(16, 64), 256, 0, stream>>>(qw, kw, vt, v_mask, q_mask, out);
    attn_kernel<5><<<dim3(16, 64), 256, 0, stream>>>(qw, kw, vt, v_mask, q_mask, out);
    // real kernel LAST: writes every output row
    attn_kernel<0><<<dim3(16, 64), 256, 0, stream>>>(qw, kw, vt, v_mask, q_mask, out);
}

// Round 8
// 384.949 us; speedup vs baseline: 1.5047x; 1.5047x over previous
//
#include <hip/hip_runtime.h>

#define S_LEN 2048
#define NHEAD 16

typedef float f32x4 __attribute__((ext_vector_type(4)));
typedef __bf16 bf16x8 __attribute__((ext_vector_type(8)));
typedef __bf16 bf16x4 __attribute__((ext_vector_type(4)));

#define AS1 __attribute__((address_space(1)))
#define AS3 __attribute__((address_space(3)))

// async 16B/lane global->LDS; lds base wave-uniform (dest = base + lane*16)
__device__ __forceinline__ void gl2lds16(const void* g, void* l) {
    __builtin_amdgcn_global_load_lds((const AS1 unsigned int*)g,
                                     (AS3 unsigned int*)l, 16, 0, 0);
}
// barrier leaving newest N vmem loads in flight (proj kernel)
__device__ __forceinline__ void wb_leave4() {
    asm volatile("s_waitcnt vmcnt(4)\n\ts_barrier" ::: "memory");
}
__device__ __forceinline__ void wb_drain() {
    asm volatile("s_waitcnt vmcnt(0)\n\ts_barrier" ::: "memory");
}

// ---------------- cast+swizzle A: q,k,v fp32[8192][1024] -> bf16, 16B chunks
// within each 64-elem k-segment permuted by (chunk ^ row&7) -------------------
__global__ __launch_bounds__(256) void cast_swizzle_kernel(
    const float* __restrict__ q, const float* __restrict__ k,
    const float* __restrict__ v, __bf16* __restrict__ out)
{
    int gid = blockIdx.x * 256 + threadIdx.x;
    int z   = gid >> 20;
    int rem = gid & 1048575;
    int r   = rem >> 7;
    int c   = rem & 127;
    const float* src = (z == 0 ? q : z == 1 ? k : v) + (size_t)r * 1024 + c * 8;
    float4 a = *(const float4*)src;
    float4 b = *(const float4*)(src + 4);
    bf16x8 t;
    t[0] = (__bf16)a.x; t[1] = (__bf16)a.y; t[2] = (__bf16)a.z; t[3] = (__bf16)a.w;
    t[4] = (__bf16)b.x; t[5] = (__bf16)b.y; t[6] = (__bf16)b.z; t[7] = (__bf16)b.w;
    int cp = (c & ~7) | ((c ^ r) & 7);
    *(bf16x8*)(out + (size_t)z * 8388608 + (size_t)r * 1024 + cp * 8) = t;
}

// ---------------- W transpose+cast+swizzle: W[k][n] f32 -> Wt[n][k] bf16 -----
__global__ __launch_bounds__(256) void transpose_cast_kernel(
    const float* __restrict__ W0, const float* __restrict__ W1,
    const float* __restrict__ W2, __bf16* __restrict__ Wt)
{
    int z = blockIdx.z;
    const float* W = (z == 0 ? W0 : z == 1 ? W1 : W2);
    __bf16* out = Wt + (size_t)z * 1048576;
    __shared__ float tile[32][33];
    int bx = blockIdx.x, by = blockIdx.y;
    int tid = threadIdx.x;
    int tx = tid & 31, ty = tid >> 5;
    for (int i = 0; i < 32; i += 8)
        tile[ty + i][tx] = W[(size_t)(by * 32 + ty + i) * 1024 + bx * 32 + tx];
    __syncthreads();
    if (tid < 128) {
        int nl = tid >> 2, kc = tid & 3;
        int n = bx * 32 + nl;
        int kbase = by * 32 + kc * 8;
        bf16x8 t;
        for (int j = 0; j < 8; j++) t[j] = (__bf16)tile[kc * 8 + j][nl];
        int cp = ((kbase >> 3) ^ n) & 7;
        *(bf16x8*)(out + (size_t)n * 1024 + (kbase & ~63) + cp * 8) = t;
    }
}

// ---------------- fused projection GEMM (z = 0:Q, 1:K, 2:V) ------------------
__global__ __launch_bounds__(256, 3) void proj_gemm_kernel(
    const __bf16* __restrict__ Abf, const __bf16* __restrict__ Wt,
    __bf16* __restrict__ qw, __bf16* __restrict__ kw, __bf16* __restrict__ vt)
{
    int z = blockIdx.z;
    const __bf16* A = Abf + (size_t)z * 8388608;
    const __bf16* B = Wt + (size_t)z * 1048576;
    __shared__ __align__(16) char smem[49152];

    int tid = threadIdx.x;
    int bm = blockIdx.x, bn = blockIdx.y;
    int wave = tid >> 6, lane = tid & 63;
    int wm = (wave >> 1) * 64, wn = (wave & 1) * 64;
    int lrow = lane & 15;
    int q4 = lane >> 4;
    int l4r = lane >> 2, j4 = lane & 3;

    auto pf = [&](int kb) {
        int sl = kb % 3;
        int k0 = kb * 32;
        int segbyte = (k0 >> 6) * 128;
        int cbase = (k0 & 32) >> 3;
        for (int i = 0; i < 2; i++) {
            int r = wave * 32 + i * 16 + l4r;
            int cl = j4 ^ ((r >> 1) & 3);
            int phys = ((cbase + cl) ^ r) & 7;
            gl2lds16((const char*)A + (size_t)(bm * 128 + r) * 2048 + segbyte + phys * 16,
                     smem + sl * 8192 + wave * 2048 + i * 1024);
            gl2lds16((const char*)B + (size_t)(bn * 128 + r) * 2048 + segbyte + phys * 16,
                     smem + 24576 + sl * 8192 + wave * 2048 + i * 1024);
        }
    };

    f32x4 zero = {0.f, 0.f, 0.f, 0.f};
    f32x4 acc[4][4];
    for (int mt = 0; mt < 4; mt++)
        for (int nt = 0; nt < 4; nt++) acc[mt][nt] = zero;

    pf(0); pf(1);
    __syncthreads();
    for (int kb = 0; kb < 32; kb++) {
        if (kb == 31) wb_drain(); else wb_leave4();
        if (kb + 2 < 32) pf(kb + 2);
        int sA = (kb % 3) * 8192, sB = 24576 + (kb % 3) * 8192;
        bf16x8 af[4], bfv[4];
        for (int mt = 0; mt < 4; mt++) {
            int r = wm + mt * 16 + lrow;
            af[mt] = *(const bf16x8*)(smem + sA + r * 64 + (q4 ^ ((r >> 1) & 3)) * 16);
        }
        for (int nt = 0; nt < 4; nt++) {
            int r = wn + nt * 16 + lrow;
            bfv[nt] = *(const bf16x8*)(smem + sB + r * 64 + (q4 ^ ((r >> 1) & 3)) * 16);
        }
        for (int mt = 0; mt < 4; mt++)
            for (int nt = 0; nt < 4; nt++)
                acc[mt][nt] = __builtin_amdgcn_mfma_f32_16x16x32_bf16(
                    af[mt], bfv[nt], acc[mt][nt], 0, 0, 0);
    }
    __syncthreads();
    __bf16* T = (__bf16*)smem;     // row stride 136 elems (272 B)

    float oscale = (z == 0) ? 0.125f : 1.0f;
    int rowoff = q4 * 4;
    int b = bm >> 4;
    int s_base = (bm & 15) * 128;
    if (z < 2) {
        for (int mt = 0; mt < 4; mt++) {
            for (int nt = 0; nt < 4; nt++) {
                int n_local = wn + nt * 16 + lrow;
                int hl = n_local >> 6, d = n_local & 63;
                for (int reg = 0; reg < 4; reg++) {
                    int s_local = wm + mt * 16 + rowoff + reg;
                    int s = s_base + s_local;
                    int dp = (d & 7) | ((((d >> 3) ^ s) & 7) << 3);
                    T[s_local * 136 + hl * 64 + dp] = (__bf16)(acc[mt][nt][reg] * oscale);
                }
            }
        }
        __syncthreads();
        char* gq = (char*)(z == 0 ? qw : kw);
        for (int i = 0; i < 8; i++) {
            int id = tid + i * 256;
            int hl = id >> 10, r = (id >> 3) & 127, j = id & 7;
            float4 val = *(float4*)((char*)T + r * 272 + hl * 128 + j * 16);
            *(float4*)(gq + ((size_t)((b * 16 + bn * 2 + hl) * 2048) + s_base + r) * 128
                          + j * 16) = val;
        }
    } else {
        for (int mt = 0; mt < 4; mt++) {
            int s0 = wm + mt * 16 + rowoff;
            int seg = s0 >> 6, j0 = s0 & 63;
            for (int nt = 0; nt < 4; nt++) {
                int n_local = wn + nt * 16 + lrow;
                int d = n_local & 63;
                int hi = ((j0 >> 3) ^ d) & 7;
                bf16x4 pk;
                for (int reg = 0; reg < 4; reg++) pk[reg] = (__bf16)acc[mt][nt][reg];
                *(bf16x4*)&T[n_local * 136 + seg * 64 + hi * 8 + (j0 & 7)] = pk;
            }
        }
        __syncthreads();
        char* gv = (char*)vt;
        for (int i = 0; i < 8; i++) {
            int id = tid + i * 256;
            int nl = id >> 4, j = id & 15;
            int hl = nl >> 6, dv = nl & 63;
            float4 val = *(float4*)((char*)T + nl * 272 + j * 16);
            *(float4*)(gv + (((size_t)((b * 16 + bn * 2 + hl) * 64 + dv)) * 2048 + s_base) * 2
                          + j * 16) = val;
        }
    }
}

// ---------------- flash attention, round 8: register-prefetch skew -----------
// r7's counted-vmcnt LDS pipeline was WRONG (compiler-issued vmem ops pollute
// the FIFO count -> stale tiles). Same skew idea, robust mechanism: all K/V
// fragments loaded per-lane global->VGPR one tile AHEAD, so the compiler's own
// (always-correct) waitcnt insertion lands after a full iteration of
// independent work. Iteration j:
//   issue loads K(j+1), V(j)          (16 global loads, consumed next iter)
//   softmax(j-1)                      (VALU; overlaps those loads' latency)
//   QK(j)                             (pure-register MFMAs: kcur arrived iter j-1)
//   PV(j-1)                           (P LDS write->read spans QK; vprev in regs)
// No barriers, no inline asm, no shared K/V: waves fully independent.
// LDS = 8KB (wave-private P only). ~200 VGPR live -> launch_bounds(256,2)
// (cap 256; do NOT use 3 -- r1 showed it collapses the allocator to spill).
// Numerics verbatim r5 (same loads, same math, same order per tile).
__global__ __launch_bounds__(256, 2) void attn_kernel(
    const __bf16* __restrict__ QW, const __bf16* __restrict__ KW,
    const __bf16* __restrict__ VT, const float* __restrict__ v_mask,
    const float* __restrict__ q_mask, float* __restrict__ out)
{
    int lin = blockIdx.x + (blockIdx.y << 4);
    int xcd = lin & 7;
    int jj  = lin >> 3;
    int bh  = (xcd << 3) + (jj >> 4);
    int bx  = jj & 15;
    int b = bh >> 4, h = bh & 15;

    __shared__ __align__(16) char lds[8192];   // 4 waves x 2KB P
    int tid = threadIdx.x;
    int wave = tid >> 6, lane = tid & 63;
    int mloc = lane & 15, q4 = lane >> 4;
    int rowoff = q4 * 4, x7 = mloc & 7;
    char* Pme = lds + wave * 2048;

    const char* Krow = (const char*)KW + (size_t)bh * 2048 * 128;
    const char* Vrow = (const char*)VT + (size_t)bh * 64 * 4096;
    const float* vmrow = v_mask + (size_t)b * 2048;

    f32x4 zero = {0.f, 0.f, 0.f, 0.f};

    for (int p = 0; p < 2; p++) {
        int qb = p ? (31 - bx) : bx;
        const char* Qrow = (const char*)QW +
                           ((size_t)bh * 2048 + qb * 64 + wave * 16) * 128;
        bf16x8 qfr[2];
        for (int kc = 0; kc < 2; kc++)
            qfr[kc] = *(const bf16x8*)(Qrow + mloc * 128 + (((kc * 4 + q4) ^ x7) << 4));

        // prologue: K(0) -> kcur (one cold-latency hit per phase); vm(0) -> vmP
        bf16x8 kcur[2][4];
        for (int kc = 0; kc < 2; kc++)
            for (int m = 0; m < 4; m++)
                kcur[kc][m] = *(const bf16x8*)(Krow +
                    (size_t)(m * 16 + mloc) * 128 + (((kc * 4 + q4) ^ x7) << 4));
        float4 vmP[4];
        for (int m = 0; m < 4; m++)
            vmP[m] = *(const float4*)(vmrow + m * 16 + rowoff);

        f32x4 o_acc[4];
        for (int nt = 0; nt < 4; nt++) o_acc[nt] = zero;
        f32x4 sacc[4];
        float lt = 0.f;
        bf16x8 vprev[2][4];   // V(j-1), consumed by PV(j-1)

        for (int j = 0; j <= qb; j++) {
            // A) prefetch: K(j+1) and V(j) (V(j) consumed NEXT iteration)
            bf16x8 knext[2][4], vnext[2][4];
            bool hasK = (j + 1 <= qb);
            if (hasK)
                for (int kc = 0; kc < 2; kc++)
                    for (int m = 0; m < 4; m++)
                        knext[kc][m] = *(const bf16x8*)(Krow +
                            (size_t)((j + 1) * 64 + m * 16 + mloc) * 128 +
                            (((kc * 4 + q4) ^ x7) << 4));
            for (int kc = 0; kc < 2; kc++)
                for (int nt = 0; nt < 4; nt++)
                    vnext[kc][nt] = *(const bf16x8*)(Vrow +
                        (size_t)(nt * 16 + mloc) * 4096 + (size_t)j * 128 +
                        (((kc * 4 + q4) ^ x7) << 4));

            // B) softmax(j-1): sacc holds tile j-1 scores; vmP holds vm(j-1)
            if (j >= 1) {
                for (int m = 0; m < 4; m++) {
                    float pen[4];
                    pen[0] = fmaf(1.0f - vmP[m].x, 1.0e9f, 12.0f);
                    pen[1] = fmaf(1.0f - vmP[m].y, 1.0e9f, 12.0f);
                    pen[2] = fmaf(1.0f - vmP[m].z, 1.0e9f, 12.0f);
                    pen[3] = fmaf(1.0f - vmP[m].w, 1.0e9f, 12.0f);
                    float pv[4];
                    for (int reg = 0; reg < 4; reg++)
                        pv[reg] = __expf(sacc[m][reg] - pen[reg]);
                    lt += (pv[0] + pv[1]) + (pv[2] + pv[3]);
                    bf16x4 pk;
                    for (int reg = 0; reg < 4; reg++) pk[reg] = (__bf16)pv[reg];
                    *(bf16x4*)(Pme + mloc * 128 +
                               (((m * 2 + (q4 >> 1)) ^ x7) << 4) + (q4 & 1) * 8) = pk;
                }
                for (int m = 0; m < 4; m++)
                    vmP[m] = *(const float4*)(vmrow + j * 64 + m * 16 + rowoff);
            }

            // C) QK(j): pure-register MFMAs (kcur arrived during iter j-1)
            for (int m = 0; m < 4; m++) sacc[m] = zero;
            for (int kc = 0; kc < 2; kc++)
                for (int m = 0; m < 4; m++)
                    sacc[m] = __builtin_amdgcn_mfma_f32_16x16x32_bf16(
                        kcur[kc][m], qfr[kc], sacc[m], 0, 0, 0);

            // D) PV(j-1): P write->read spans QK's MFMAs; vprev in registers
            if (j >= 1) {
                for (int kc = 0; kc < 2; kc++) {
                    bf16x8 afr = *(const bf16x8*)(Pme + mloc * 128 +
                                                  (((kc * 4 + q4) ^ x7) << 4));
                    for (int nt = 0; nt < 4; nt++)
                        o_acc[nt] = __builtin_amdgcn_mfma_f32_16x16x32_bf16(
                            afr, vprev[kc][nt], o_acc[nt], 0, 0, 0);
                }
            }

            // E) rotate prefetch registers
            if (hasK)
                for (int kc = 0; kc < 2; kc++)
                    for (int m = 0; m < 4; m++) kcur[kc][m] = knext[kc][m];
            for (int kc = 0; kc < 2; kc++)
                for (int nt = 0; nt < 4; nt++) vprev[kc][nt] = vnext[kc][nt];
        }

        // epilogue: softmax(qb) with causal zeroing + PV(qb); vmP = vm(qb)
        for (int m = 0; m < 4; m++) {
            float pen[4];
            pen[0] = fmaf(1.0f - vmP[m].x, 1.0e9f, 12.0f);
            pen[1] = fmaf(1.0f - vmP[m].y, 1.0e9f, 12.0f);
            pen[2] = fmaf(1.0f - vmP[m].z, 1.0e9f, 12.0f);
            pen[3] = fmaf(1.0f - vmP[m].w, 1.0e9f, 12.0f);
            float pv[4];
            for (int reg = 0; reg < 4; reg++)
                pv[reg] = __expf(sacc[m][reg] - pen[reg]);
            for (int reg = 0; reg < 4; reg++)
                if (m * 16 + rowoff + reg > wave * 16 + mloc) pv[reg] = 0.f;
            lt += (pv[0] + pv[1]) + (pv[2] + pv[3]);
            bf16x4 pk;
            for (int reg = 0; reg < 4; reg++) pk[reg] = (__bf16)pv[reg];
            *(bf16x4*)(Pme + mloc * 128 +
                       (((m * 2 + (q4 >> 1)) ^ x7) << 4) + (q4 & 1) * 8) = pk;
        }
        for (int kc = 0; kc < 2; kc++) {
            bf16x8 afr = *(const bf16x8*)(Pme + mloc * 128 +
                                          (((kc * 4 + q4) ^ x7) << 4));
            for (int nt = 0; nt < 4; nt++)
                o_acc[nt] = __builtin_amdgcn_mfma_f32_16x16x32_bf16(
                    afr, vprev[kc][nt], o_acc[nt], 0, 0, 0);
        }

        // l: sum over q4 key-groups -> every lane holds l(query mloc)
        lt += __shfl_xor(lt, 16);
        lt += __shfl_xor(lt, 32);

        // degenerate queries (entire causal window masked): reference
        // softmaxes uniformly over {window} U {unmasked future} (all logits
        // exactly -1e9). Wave-local indicator pass, V from global (rare).
        if (__any(lt == 0.0f)) {
            float l2 = 0.f;
            bool degrow = (lt == 0.0f);
            int qrow = qb * 64 + wave * 16 + mloc;
            for (int kb2 = 0; kb2 < 32; kb2++) {
                bf16x8 vfr[4][2];
                for (int nt = 0; nt < 4; nt++)
                    for (int kc = 0; kc < 2; kc++)
                        vfr[nt][kc] = *(const bf16x8*)(Vrow +
                            (size_t)(nt * 16 + mloc) * 4096 +
                            kb2 * 128 + (((kc * 4 + q4) ^ x7) << 4));
                for (int kc = 0; kc < 2; kc++) {
                    const float* vmp = vmrow + kb2 * 64 + kc * 32 + q4 * 8;
                    float4 va = *(const float4*)vmp;
                    float4 vb4 = *(const float4*)(vmp + 4);
                    float vmj[8] = {va.x, va.y, va.z, va.w,
                                    vb4.x, vb4.y, vb4.z, vb4.w};
                    int kg0 = kb2 * 64 + kc * 32 + q4 * 8;
                    bf16x8 af;
                    float cnt = 0.f;
                    for (int jx = 0; jx < 8; jx++) {
                        float ind = degrow ? ((kg0 + jx <= qrow) ? 1.0f : vmj[jx]) : 0.0f;
                        af[jx] = (__bf16)ind;
                        cnt += ind;
                    }
                    l2 += cnt;
                    for (int nt = 0; nt < 4; nt++)
                        o_acc[nt] = __builtin_amdgcn_mfma_f32_16x16x32_bf16(
                            af, vfr[nt][kc], o_acc[nt], 0, 0, 0);
                }
            }
            l2 += __shfl_xor(l2, 16);
            l2 += __shfl_xor(l2, 32);
            if (degrow) lt = l2;
        }

        // epilogue: direct scaled store (query = rowoff+reg, dv = nt*16+mloc)
        float sc[4];
        for (int reg = 0; reg < 4; reg++) {
            float lq = __shfl(lt, rowoff + reg);
            sc[reg] = q_mask[b * 2048 + qb * 64 + wave * 16 + rowoff + reg] / lq;
        }
        for (int nt = 0; nt < 4; nt++)
            for (int reg = 0; reg < 4; reg++)
                out[((size_t)(b * 2048 + qb * 64 + wave * 16 + rowoff + reg)) * 1024 +
                    h * 64 + nt * 16 + mloc] = o_acc[nt][reg] * sc[reg];
        // no barrier needed between phases: P is wave-private, K/V in regs
    }
}

// ---------------- launch ------------------------------------------------------
extern "C" void kernel_launch(void* const* d_in, const int* in_sizes, int n_in,
                              void* d_out, int out_size, void* d_ws, size_t ws_size,
                              hipStream_t stream)
{
    const float* q      = (const float*)d_in[0];
    const float* k      = (const float*)d_in[1];
    const float* v      = (const float*)d_in[2];
    const float* v_mask = (const float*)d_in[3];
    const float* q_mask = (const float*)d_in[4];
    const float* Wq     = (const float*)d_in[5];
    const float* Wk     = (const float*)d_in[6];
    const float* Wv     = (const float*)d_in[7];
    float* out = (float*)d_out;

    __bf16* Abf = (__bf16*)d_ws;                 // 3 x 8192 x 1024
    __bf16* Wt  = Abf + (size_t)3 * 8388608;     // 3 x 1024 x 1024
    __bf16* qw  = Wt + (size_t)3 * 1048576;      // [B*H][S][64] (x0.125)
    __bf16* kw  = qw + (size_t)8388608;
    __bf16* vt  = kw + (size_t)8388608;          // [B*H][64][S]

    cast_swizzle_kernel<<<12288, 256, 0, stream>>>(q, k, v, Abf);
    transpose_cast_kernel<<<dim3(32, 32, 3), 256, 0, stream>>>(Wq, Wk, Wv, Wt);
    proj_gemm_kernel<<<dim3(64, 8, 3), 256, 0, stream>>>(Abf, Wt, qw, kw, vt);
    attn_kernel<<<dim3(16, 64), 256, 0, stream>>>(qw, kw, vt, v_mask, q_mask, out);
}

// Round 9
// 313.890 us; speedup vs baseline: 1.8453x; 1.2264x over previous
//
#include <hip/hip_runtime.h>

#define S_LEN 2048
#define NHEAD 16

typedef float f32x4 __attribute__((ext_vector_type(4)));
typedef __bf16 bf16x8 __attribute__((ext_vector_type(8)));
typedef __bf16 bf16x4 __attribute__((ext_vector_type(4)));

#define AS1 __attribute__((address_space(1)))
#define AS3 __attribute__((address_space(3)))

// async 16B/lane global->LDS; lds base wave-uniform (dest = base + lane*16)
__device__ __forceinline__ void gl2lds16(const void* g, void* l) {
    __builtin_amdgcn_global_load_lds((const AS1 unsigned int*)g,
                                     (AS3 unsigned int*)l, 16, 0, 0);
}
// barrier leaving newest N vmem loads in flight (proj kernel)
__device__ __forceinline__ void wb_leave4() {
    asm volatile("s_waitcnt vmcnt(4)\n\ts_barrier" ::: "memory");
}
__device__ __forceinline__ void wb_drain() {
    asm volatile("s_waitcnt vmcnt(0)\n\ts_barrier" ::: "memory");
}

// ---------------- cast+swizzle A: q,k,v fp32[8192][1024] -> bf16, 16B chunks
// within each 64-elem k-segment permuted by (chunk ^ row&7) -------------------
__global__ __launch_bounds__(256) void cast_swizzle_kernel(
    const float* __restrict__ q, const float* __restrict__ k,
    const float* __restrict__ v, __bf16* __restrict__ out)
{
    int gid = blockIdx.x * 256 + threadIdx.x;
    int z   = gid >> 20;
    int rem = gid & 1048575;
    int r   = rem >> 7;
    int c   = rem & 127;
    const float* src = (z == 0 ? q : z == 1 ? k : v) + (size_t)r * 1024 + c * 8;
    float4 a = *(const float4*)src;
    float4 b = *(const float4*)(src + 4);
    bf16x8 t;
    t[0] = (__bf16)a.x; t[1] = (__bf16)a.y; t[2] = (__bf16)a.z; t[3] = (__bf16)a.w;
    t[4] = (__bf16)b.x; t[5] = (__bf16)b.y; t[6] = (__bf16)b.z; t[7] = (__bf16)b.w;
    int cp = (c & ~7) | ((c ^ r) & 7);
    *(bf16x8*)(out + (size_t)z * 8388608 + (size_t)r * 1024 + cp * 8) = t;
}

// ---------------- W transpose+cast+swizzle: W[k][n] f32 -> Wt[n][k] bf16 -----
__global__ __launch_bounds__(256) void transpose_cast_kernel(
    const float* __restrict__ W0, const float* __restrict__ W1,
    const float* __restrict__ W2, __bf16* __restrict__ Wt)
{
    int z = blockIdx.z;
    const float* W = (z == 0 ? W0 : z == 1 ? W1 : W2);
    __bf16* out = Wt + (size_t)z * 1048576;
    __shared__ float tile[32][33];
    int bx = blockIdx.x, by = blockIdx.y;
    int tid = threadIdx.x;
    int tx = tid & 31, ty = tid >> 5;
    for (int i = 0; i < 32; i += 8)
        tile[ty + i][tx] = W[(size_t)(by * 32 + ty + i) * 1024 + bx * 32 + tx];
    __syncthreads();
    if (tid < 128) {
        int nl = tid >> 2, kc = tid & 3;
        int n = bx * 32 + nl;
        int kbase = by * 32 + kc * 8;
        bf16x8 t;
        for (int j = 0; j < 8; j++) t[j] = (__bf16)tile[kc * 8 + j][nl];
        int cp = ((kbase >> 3) ^ n) & 7;
        *(bf16x8*)(out + (size_t)n * 1024 + (kbase & ~63) + cp * 8) = t;
    }
}

// ---------------- fused projection GEMM (z = 0:Q, 1:K, 2:V) ------------------
__global__ __launch_bounds__(256, 3) void proj_gemm_kernel(
    const __bf16* __restrict__ Abf, const __bf16* __restrict__ Wt,
    __bf16* __restrict__ qw, __bf16* __restrict__ kw, __bf16* __restrict__ vt)
{
    int z = blockIdx.z;
    const __bf16* A = Abf + (size_t)z * 8388608;
    const __bf16* B = Wt + (size_t)z * 1048576;
    __shared__ __align__(16) char smem[49152];

    int tid = threadIdx.x;
    int bm = blockIdx.x, bn = blockIdx.y;
    int wave = tid >> 6, lane = tid & 63;
    int wm = (wave >> 1) * 64, wn = (wave & 1) * 64;
    int lrow = lane & 15;
    int q4 = lane >> 4;
    int l4r = lane >> 2, j4 = lane & 3;

    auto pf = [&](int kb) {
        int sl = kb % 3;
        int k0 = kb * 32;
        int segbyte = (k0 >> 6) * 128;
        int cbase = (k0 & 32) >> 3;
        for (int i = 0; i < 2; i++) {
            int r = wave * 32 + i * 16 + l4r;
            int cl = j4 ^ ((r >> 1) & 3);
            int phys = ((cbase + cl) ^ r) & 7;
            gl2lds16((const char*)A + (size_t)(bm * 128 + r) * 2048 + segbyte + phys * 16,
                     smem + sl * 8192 + wave * 2048 + i * 1024);
            gl2lds16((const char*)B + (size_t)(bn * 128 + r) * 2048 + segbyte + phys * 16,
                     smem + 24576 + sl * 8192 + wave * 2048 + i * 1024);
        }
    };

    f32x4 zero = {0.f, 0.f, 0.f, 0.f};
    f32x4 acc[4][4];
    for (int mt = 0; mt < 4; mt++)
        for (int nt = 0; nt < 4; nt++) acc[mt][nt] = zero;

    pf(0); pf(1);
    __syncthreads();
    for (int kb = 0; kb < 32; kb++) {
        if (kb == 31) wb_drain(); else wb_leave4();
        if (kb + 2 < 32) pf(kb + 2);
        int sA = (kb % 3) * 8192, sB = 24576 + (kb % 3) * 8192;
        bf16x8 af[4], bfv[4];
        for (int mt = 0; mt < 4; mt++) {
            int r = wm + mt * 16 + lrow;
            af[mt] = *(const bf16x8*)(smem + sA + r * 64 + (q4 ^ ((r >> 1) & 3)) * 16);
        }
        for (int nt = 0; nt < 4; nt++) {
            int r = wn + nt * 16 + lrow;
            bfv[nt] = *(const bf16x8*)(smem + sB + r * 64 + (q4 ^ ((r >> 1) & 3)) * 16);
        }
        for (int mt = 0; mt < 4; mt++)
            for (int nt = 0; nt < 4; nt++)
                acc[mt][nt] = __builtin_amdgcn_mfma_f32_16x16x32_bf16(
                    af[mt], bfv[nt], acc[mt][nt], 0, 0, 0);
    }
    __syncthreads();
    __bf16* T = (__bf16*)smem;     // row stride 136 elems (272 B)

    float oscale = (z == 0) ? 0.125f : 1.0f;
    int rowoff = q4 * 4;
    int b = bm >> 4;
    int s_base = (bm & 15) * 128;
    if (z < 2) {
        for (int mt = 0; mt < 4; mt++) {
            for (int nt = 0; nt < 4; nt++) {
                int n_local = wn + nt * 16 + lrow;
                int hl = n_local >> 6, d = n_local & 63;
                for (int reg = 0; reg < 4; reg++) {
                    int s_local = wm + mt * 16 + rowoff + reg;
                    int s = s_base + s_local;
                    int dp = (d & 7) | ((((d >> 3) ^ s) & 7) << 3);
                    T[s_local * 136 + hl * 64 + dp] = (__bf16)(acc[mt][nt][reg] * oscale);
                }
            }
        }
        __syncthreads();
        char* gq = (char*)(z == 0 ? qw : kw);
        for (int i = 0; i < 8; i++) {
            int id = tid + i * 256;
            int hl = id >> 10, r = (id >> 3) & 127, j = id & 7;
            float4 val = *(float4*)((char*)T + r * 272 + hl * 128 + j * 16);
            *(float4*)(gq + ((size_t)((b * 16 + bn * 2 + hl) * 2048) + s_base + r) * 128
                          + j * 16) = val;
        }
    } else {
        for (int mt = 0; mt < 4; mt++) {
            int s0 = wm + mt * 16 + rowoff;
            int seg = s0 >> 6, j0 = s0 & 63;
            for (int nt = 0; nt < 4; nt++) {
                int n_local = wn + nt * 16 + lrow;
                int d = n_local & 63;
                int hi = ((j0 >> 3) ^ d) & 7;
                bf16x4 pk;
                for (int reg = 0; reg < 4; reg++) pk[reg] = (__bf16)acc[mt][nt][reg];
                *(bf16x4*)&T[n_local * 136 + seg * 64 + hi * 8 + (j0 & 7)] = pk;
            }
        }
        __syncthreads();
        char* gv = (char*)vt;
        for (int i = 0; i < 8; i++) {
            int id = tid + i * 256;
            int nl = id >> 4, j = id & 15;
            int hl = nl >> 6, dv = nl & 63;
            float4 val = *(float4*)((char*)T + nl * 272 + j * 16);
            *(float4*)(gv + (((size_t)((b * 16 + bn * 2 + hl) * 64 + dv)) * 2048 + s_base) * 2
                          + j * 16) = val;
        }
    }
}

// ---------------- flash attention, round 9: skewed pipeline, SOUND vmcnt -----
// r6 ablation: per-tile wait-chain. r7 (this schedule) failed because the
// vmcnt stream was polluted: in-loop v_mask GLOBAL loads and -- the killer --
// the phase-0 epilogue's 16 global STORES (stores increment vmcnt!) leaked
// into phase 1's counted waits, so vmcnt(12) passed without draining stage(0).
// r8 (register pipeline) spilled (WRITE 33->112MB). This round: r7's skewed
// schedule with a vmem-accounting discipline:
//   * the kv-loop's ONLY vmem ops are the gl2lds stages (4/stage):
//     v_mask lives in LDS (staged once per block; shared by both phases),
//     vm4 reads are ds_reads, Q/q_mask loads are outside the loop.
//   * phase boundary drains vmcnt(0)+lgkmcnt(0) so epilogue stores and
//     degenerate-pass global loads never leak into the next phase's counts.
// Schedule per iteration j: [wait 4*nst; barrier] K-ds_read(j) || softmax(j-1)
// -> QK(j) (reg MFMAs) || PV(j-1) -> [barrier] stage(j+3). Outstanding at top
// of j = stages {j,j+1,j+2} (each 4 ops) -> wait leaves 4*|{j+1,j+2}<=qb|.
// Verified by hand for qb=0,1,2,3 and steady state; phase-0 prologue vms(2)+
// qfr(2) ops sit oldest and drain with stage 0.
// LDS 80KB (4 K-slots + 4 V-slots + P + vms) -> 2 blocks/CU. VGPR ~130.
__global__ __launch_bounds__(256, 2) void attn_kernel(
    const __bf16* __restrict__ QW, const __bf16* __restrict__ KW,
    const __bf16* __restrict__ VT, const float* __restrict__ v_mask,
    const float* __restrict__ q_mask, float* __restrict__ out)
{
    int lin = blockIdx.x + (blockIdx.y << 4);
    int xcd = lin & 7;
    int jj  = lin >> 3;
    int bh  = (xcd << 3) + (jj >> 4);
    int bx  = jj & 15;
    int b = bh >> 4, h = bh & 15;

    __shared__ __align__(16) char lds[81920];
    // K slots: lds + slot*8192            (4 x 8KB)
    // V slots: lds + 32768 + slot*8192    (4 x 8KB)
    // P:       lds + 65536 + wave*2048    (8KB)
    // vms:     lds + 73728                (8KB = v_mask row for this b)
    char*  Pw  = lds + 65536;
    float* vms = (float*)(lds + 73728);

    int tid = threadIdx.x;
    int wave = tid >> 6, lane = tid & 63;
    int mloc = lane & 15, q4 = lane >> 4;
    int rowoff = q4 * 4, x7 = mloc & 7;
    char* Pme = Pw + wave * 2048;

    const char* Krow = (const char*)KW + (size_t)bh * 2048 * 128;
    const char* Vrow = (const char*)VT + (size_t)bh * 64 * 4096;
    const float* vmrow = v_mask + (size_t)b * 2048;

    int id0 = tid, id1 = tid + 256;

    auto stage = [&](int kb, int slot) {
        char* kd = lds + slot * 8192;
        char* vd = lds + 32768 + slot * 8192;
        gl2lds16(Krow + (size_t)(kb * 64 + (id0 >> 3)) * 128 + (id0 & 7) * 16,
                 kd + id0 * 16);
        gl2lds16(Krow + (size_t)(kb * 64 + (id1 >> 3)) * 128 + (id1 & 7) * 16,
                 kd + id1 * 16);
        gl2lds16(Vrow + (size_t)(id0 >> 3) * 4096 + (size_t)kb * 128 + (id0 & 7) * 16,
                 vd + id0 * 16);
        gl2lds16(Vrow + (size_t)(id1 >> 3) * 4096 + (size_t)kb * 128 + (id1 & 7) * 16,
                 vd + id1 * 16);
    };

    // v_mask row -> LDS once per block (both phases share b). 2 vmem ops/lane.
    gl2lds16((const char*)vmrow + id0 * 16, (char*)vms + id0 * 16);
    gl2lds16((const char*)vmrow + 4096 + id0 * 16, (char*)vms + 4096 + id0 * 16);

    f32x4 zero = {0.f, 0.f, 0.f, 0.f};

    for (int p = 0; p < 2; p++) {
        int qb = p ? (31 - bx) : bx;
        const char* Qrow = (const char*)QW +
                           ((size_t)bh * 2048 + qb * 64 + wave * 16) * 128;
        bf16x8 qfr[2];
        for (int kc = 0; kc < 2; kc++)
            qfr[kc] = *(const bf16x8*)(Qrow + mloc * 128 + (((kc * 4 + q4) ^ x7) << 4));

        stage(0, 0);
        if (qb >= 1) stage(1, 1);
        if (qb >= 2) stage(2, 2);

        f32x4 o_acc[4];
        for (int nt = 0; nt < 4; nt++) o_acc[nt] = zero;
        f32x4 sacc[4];
        float lt = 0.f;

        for (int j = 0; j <= qb; j++) {
            // vmem stream is ONLY gl2lds stages (plus oldest prologue ops at
            // j==0, which drain together with stage 0). Outstanding at this
            // point: stages {j, j+1, j+2} clipped to <=qb.
            int nst = ((j + 1 <= qb) ? 1 : 0) + ((j + 2 <= qb) ? 1 : 0);
            if (nst == 2)
                asm volatile("s_waitcnt vmcnt(8)\n\ts_barrier" ::: "memory");
            else if (nst == 1)
                asm volatile("s_waitcnt vmcnt(4)\n\ts_barrier" ::: "memory");
            else
                asm volatile("s_waitcnt vmcnt(0)\n\ts_barrier" ::: "memory");

            // K fragment ds_reads for tile j (latency overlaps softmax below)
            const char* Kls = lds + (j & 3) * 8192;
            bf16x8 kfr[2][4];
            for (int kc = 0; kc < 2; kc++)
                for (int m = 0; m < 4; m++)
                    kfr[kc][m] = *(const bf16x8*)(Kls + (m * 16 + mloc) * 128 +
                                                  (((kc * 4 + q4) ^ x7) << 4));

            // softmax(j-1): sacc holds tile j-1 scores; vm from LDS
            if (j >= 1) {
                for (int m = 0; m < 4; m++) {
                    float4 vm4 = *(const float4*)&vms[(j - 1) * 64 + m * 16 + rowoff];
                    float pen[4];
                    pen[0] = fmaf(1.0f - vm4.x, 1.0e9f, 12.0f);
                    pen[1] = fmaf(1.0f - vm4.y, 1.0e9f, 12.0f);
                    pen[2] = fmaf(1.0f - vm4.z, 1.0e9f, 12.0f);
                    pen[3] = fmaf(1.0f - vm4.w, 1.0e9f, 12.0f);
                    float pv[4];
                    for (int reg = 0; reg < 4; reg++)
                        pv[reg] = __expf(sacc[m][reg] - pen[reg]);
                    lt += (pv[0] + pv[1]) + (pv[2] + pv[3]);
                    bf16x4 pk;
                    for (int reg = 0; reg < 4; reg++) pk[reg] = (__bf16)pv[reg];
                    *(bf16x4*)(Pme + mloc * 128 +
                               (((m * 2 + (q4 >> 1)) ^ x7) << 4) + (q4 & 1) * 8) = pk;
                }
            }

            // QK(j): overwrite sacc (softmax above already consumed it)
            for (int m = 0; m < 4; m++) sacc[m] = zero;
            for (int kc = 0; kc < 2; kc++)
                for (int m = 0; m < 4; m++)
                    sacc[m] = __builtin_amdgcn_mfma_f32_16x16x32_bf16(
                        kfr[kc][m], qfr[kc], sacc[m], 0, 0, 0);

            // PV(j-1): P write->read spans QK's MFMAs; V from slot (j-1)&3
            if (j >= 1) {
                const char* Vp = lds + 32768 + ((j - 1) & 3) * 8192;
                for (int kc = 0; kc < 2; kc++) {
                    bf16x8 afr = *(const bf16x8*)(Pme + mloc * 128 +
                                                  (((kc * 4 + q4) ^ x7) << 4));
                    bf16x8 vfr[4];
                    for (int nt = 0; nt < 4; nt++)
                        vfr[nt] = *(const bf16x8*)(Vp + (nt * 16 + mloc) * 128 +
                                                   (((kc * 4 + q4) ^ x7) << 4));
                    for (int nt = 0; nt < 4; nt++)
                        o_acc[nt] = __builtin_amdgcn_mfma_f32_16x16x32_bf16(
                            afr, vfr[nt], o_acc[nt], 0, 0, 0);
                }
            }

            // raw barrier: every wave's reads of slot (j-1)&3 are complete
            // (consumed by MFMAs above); stage(j+3) may then overwrite it.
            asm volatile("s_barrier" ::: "memory");
            if (j + 3 <= qb) stage(j + 3, (j + 3) & 3);
        }

        // epilogue tile qb: softmax with causal zeroing + PV from slot qb&3
        for (int m = 0; m < 4; m++) {
            float4 vm4 = *(const float4*)&vms[qb * 64 + m * 16 + rowoff];
            float pen[4];
            pen[0] = fmaf(1.0f - vm4.x, 1.0e9f, 12.0f);
            pen[1] = fmaf(1.0f - vm4.y, 1.0e9f, 12.0f);
            pen[2] = fmaf(1.0f - vm4.z, 1.0e9f, 12.0f);
            pen[3] = fmaf(1.0f - vm4.w, 1.0e9f, 12.0f);
            float pv[4];
            for (int reg = 0; reg < 4; reg++)
                pv[reg] = __expf(sacc[m][reg] - pen[reg]);
            for (int reg = 0; reg < 4; reg++)
                if (m * 16 + rowoff + reg > wave * 16 + mloc) pv[reg] = 0.f;
            lt += (pv[0] + pv[1]) + (pv[2] + pv[3]);
            bf16x4 pk;
            for (int reg = 0; reg < 4; reg++) pk[reg] = (__bf16)pv[reg];
            *(bf16x4*)(Pme + mloc * 128 +
                       (((m * 2 + (q4 >> 1)) ^ x7) << 4) + (q4 & 1) * 8) = pk;
        }
        {
            const char* Vq = lds + 32768 + (qb & 3) * 8192;
            for (int kc = 0; kc < 2; kc++) {
                bf16x8 afr = *(const bf16x8*)(Pme + mloc * 128 +
                                              (((kc * 4 + q4) ^ x7) << 4));
                bf16x8 vfr[4];
                for (int nt = 0; nt < 4; nt++)
                    vfr[nt] = *(const bf16x8*)(Vq + (nt * 16 + mloc) * 128 +
                                               (((kc * 4 + q4) ^ x7) << 4));
                for (int nt = 0; nt < 4; nt++)
                    o_acc[nt] = __builtin_amdgcn_mfma_f32_16x16x32_bf16(
                        afr, vfr[nt], o_acc[nt], 0, 0, 0);
            }
        }

        // l: sum over q4 key-groups -> every lane holds l(query mloc)
        lt += __shfl_xor(lt, 16);
        lt += __shfl_xor(lt, 32);

        // degenerate queries (entire causal window masked): reference
        // softmaxes uniformly over {window} U {unmasked future} (all logits
        // exactly -1e9). Wave-local indicator pass, V from global (rare;
        // post-loop, drained at the phase boundary below).
        if (__any(lt == 0.0f)) {
            float l2 = 0.f;
            bool degrow = (lt == 0.0f);
            int qrow = qb * 64 + wave * 16 + mloc;
            for (int kb2 = 0; kb2 < 32; kb2++) {
                bf16x8 vfr[4][2];
                for (int nt = 0; nt < 4; nt++)
                    for (int kc = 0; kc < 2; kc++)
                        vfr[nt][kc] = *(const bf16x8*)(Vrow +
                            (size_t)(nt * 16 + mloc) * 4096 +
                            kb2 * 128 + (((kc * 4 + q4) ^ x7) << 4));
                for (int kc = 0; kc < 2; kc++) {
                    const float* vmp = &vms[kb2 * 64 + kc * 32 + q4 * 8];
                    float4 va = *(const float4*)vmp;
                    float4 vb4 = *(const float4*)(vmp + 4);
                    float vmj[8] = {va.x, va.y, va.z, va.w,
                                    vb4.x, vb4.y, vb4.z, vb4.w};
                    int kg0 = kb2 * 64 + kc * 32 + q4 * 8;
                    bf16x8 af;
                    float cnt = 0.f;
                    for (int jx = 0; jx < 8; jx++) {
                        float ind = degrow ? ((kg0 + jx <= qrow) ? 1.0f : vmj[jx]) : 0.0f;
                        af[jx] = (__bf16)ind;
                        cnt += ind;
                    }
                    l2 += cnt;
                    for (int nt = 0; nt < 4; nt++)
                        o_acc[nt] = __builtin_amdgcn_mfma_f32_16x16x32_bf16(
                            af, vfr[nt][kc], o_acc[nt], 0, 0, 0);
                }
            }
            l2 += __shfl_xor(l2, 16);
            l2 += __shfl_xor(l2, 32);
            if (degrow) lt = l2;
        }

        // epilogue: direct scaled store (query = rowoff+reg, dv = nt*16+mloc)
        float sc[4];
        for (int reg = 0; reg < 4; reg++) {
            float lq = __shfl(lt, rowoff + reg);
            sc[reg] = q_mask[b * 2048 + qb * 64 + wave * 16 + rowoff + reg] / lq;
        }
        for (int nt = 0; nt < 4; nt++)
            for (int reg = 0; reg < 4; reg++)
                out[((size_t)(b * 2048 + qb * 64 + wave * 16 + rowoff + reg)) * 1024 +
                    h * 64 + nt * 16 + mloc] = o_acc[nt][reg] * sc[reg];

        // PHASE BOUNDARY: full drain. Stores and degenerate-pass loads also
        // count on vmcnt -- without this drain they leak into the next
        // phase's counted waits (this was r7's correctness bug).
        asm volatile("s_waitcnt vmcnt(0) lgkmcnt(0)\n\ts_barrier" ::: "memory");
    }
}

// ---------------- launch ------------------------------------------------------
extern "C" void kernel_launch(void* const* d_in, const int* in_sizes, int n_in,
                              void* d_out, int out_size, void* d_ws, size_t ws_size,
                              hipStream_t stream)
{
    const float* q      = (const float*)d_in[0];
    const float* k      = (const float*)d_in[1];
    const float* v      = (const float*)d_in[2];
    const float* v_mask = (const float*)d_in[3];
    const float* q_mask = (const float*)d_in[4];
    const float* Wq     = (const float*)d_in[5];
    const float* Wk     = (const float*)d_in[6];
    const float* Wv     = (const float*)d_in[7];
    float* out = (float*)d_out;

    __bf16* Abf = (__bf16*)d_ws;                 // 3 x 8192 x 1024
    __bf16* Wt  = Abf + (size_t)3 * 8388608;     // 3 x 1024 x 1024
    __bf16* qw  = Wt + (size_t)3 * 1048576;      // [B*H][S][64] (x0.125)
    __bf16* kw  = qw + (size_t)8388608;
    __bf16* vt  = kw + (size_t)8388608;          // [B*H][64][S]

    cast_swizzle_kernel<<<12288, 256, 0, stream>>>(q, k, v, Abf);
    transpose_cast_kernel<<<dim3(32, 32, 3), 256, 0, stream>>>(Wq, Wk, Wv, Wt);
    proj_gemm_kernel<<<dim3(64, 8, 3), 256, 0, stream>>>(Abf, Wt, qw, kw, vt);
    attn_kernel<<<dim3(16, 64), 256, 0, stream>>>(qw, kw, vt, v_mask, q_mask, out);
}

// Round 10
// 306.499 us; speedup vs baseline: 1.8898x; 1.0241x over previous
//
#include <hip/hip_runtime.h>

#define S_LEN 2048
#define NHEAD 16

typedef float f32x4 __attribute__((ext_vector_type(4)));
typedef __bf16 bf16x8 __attribute__((ext_vector_type(8)));
typedef __bf16 bf16x4 __attribute__((ext_vector_type(4)));

#define AS1 __attribute__((address_space(1)))
#define AS3 __attribute__((address_space(3)))

// async 16B/lane global->LDS; lds base wave-uniform (dest = base + lane*16)
__device__ __forceinline__ void gl2lds16(const void* g, void* l) {
    __builtin_amdgcn_global_load_lds((const AS1 unsigned int*)g,
                                     (AS3 unsigned int*)l, 16, 0, 0);
}
// barrier leaving newest N vmem loads in flight (proj kernel)
__device__ __forceinline__ void wb_leave4() {
    asm volatile("s_waitcnt vmcnt(4)\n\ts_barrier" ::: "memory");
}
__device__ __forceinline__ void wb_drain() {
    asm volatile("s_waitcnt vmcnt(0)\n\ts_barrier" ::: "memory");
}

// ---------------- cast+swizzle A: q,k,v fp32[8192][1024] -> bf16, 16B chunks
// within each 64-elem k-segment permuted by (chunk ^ row&7) -------------------
__global__ __launch_bounds__(256) void cast_swizzle_kernel(
    const float* __restrict__ q, const float* __restrict__ k,
    const float* __restrict__ v, __bf16* __restrict__ out)
{
    int gid = blockIdx.x * 256 + threadIdx.x;
    int z   = gid >> 20;
    int rem = gid & 1048575;
    int r   = rem >> 7;
    int c   = rem & 127;
    const float* src = (z == 0 ? q : z == 1 ? k : v) + (size_t)r * 1024 + c * 8;
    float4 a = *(const float4*)src;
    float4 b = *(const float4*)(src + 4);
    bf16x8 t;
    t[0] = (__bf16)a.x; t[1] = (__bf16)a.y; t[2] = (__bf16)a.z; t[3] = (__bf16)a.w;
    t[4] = (__bf16)b.x; t[5] = (__bf16)b.y; t[6] = (__bf16)b.z; t[7] = (__bf16)b.w;
    int cp = (c & ~7) | ((c ^ r) & 7);
    *(bf16x8*)(out + (size_t)z * 8388608 + (size_t)r * 1024 + cp * 8) = t;
}

// ---------------- W transpose+cast+swizzle: W[k][n] f32 -> Wt[n][k] bf16 -----
__global__ __launch_bounds__(256) void transpose_cast_kernel(
    const float* __restrict__ W0, const float* __restrict__ W1,
    const float* __restrict__ W2, __bf16* __restrict__ Wt)
{
    int z = blockIdx.z;
    const float* W = (z == 0 ? W0 : z == 1 ? W1 : W2);
    __bf16* out = Wt + (size_t)z * 1048576;
    __shared__ float tile[32][33];
    int bx = blockIdx.x, by = blockIdx.y;
    int tid = threadIdx.x;
    int tx = tid & 31, ty = tid >> 5;
    for (int i = 0; i < 32; i += 8)
        tile[ty + i][tx] = W[(size_t)(by * 32 + ty + i) * 1024 + bx * 32 + tx];
    __syncthreads();
    if (tid < 128) {
        int nl = tid >> 2, kc = tid & 3;
        int n = bx * 32 + nl;
        int kbase = by * 32 + kc * 8;
        bf16x8 t;
        for (int j = 0; j < 8; j++) t[j] = (__bf16)tile[kc * 8 + j][nl];
        int cp = ((kbase >> 3) ^ n) & 7;
        *(bf16x8*)(out + (size_t)n * 1024 + (kbase & ~63) + cp * 8) = t;
    }
}

// ---------------- fused projection GEMM (z = 0:Q, 1:K, 2:V) ------------------
__global__ __launch_bounds__(256, 3) void proj_gemm_kernel(
    const __bf16* __restrict__ Abf, const __bf16* __restrict__ Wt,
    __bf16* __restrict__ qw, __bf16* __restrict__ kw, __bf16* __restrict__ vt)
{
    int z = blockIdx.z;
    const __bf16* A = Abf + (size_t)z * 8388608;
    const __bf16* B = Wt + (size_t)z * 1048576;
    __shared__ __align__(16) char smem[49152];

    int tid = threadIdx.x;
    int bm = blockIdx.x, bn = blockIdx.y;
    int wave = tid >> 6, lane = tid & 63;
    int wm = (wave >> 1) * 64, wn = (wave & 1) * 64;
    int lrow = lane & 15;
    int q4 = lane >> 4;
    int l4r = lane >> 2, j4 = lane & 3;

    auto pf = [&](int kb) {
        int sl = kb % 3;
        int k0 = kb * 32;
        int segbyte = (k0 >> 6) * 128;
        int cbase = (k0 & 32) >> 3;
        for (int i = 0; i < 2; i++) {
            int r = wave * 32 + i * 16 + l4r;
            int cl = j4 ^ ((r >> 1) & 3);
            int phys = ((cbase + cl) ^ r) & 7;
            gl2lds16((const char*)A + (size_t)(bm * 128 + r) * 2048 + segbyte + phys * 16,
                     smem + sl * 8192 + wave * 2048 + i * 1024);
            gl2lds16((const char*)B + (size_t)(bn * 128 + r) * 2048 + segbyte + phys * 16,
                     smem + 24576 + sl * 8192 + wave * 2048 + i * 1024);
        }
    };

    f32x4 zero = {0.f, 0.f, 0.f, 0.f};
    f32x4 acc[4][4];
    for (int mt = 0; mt < 4; mt++)
        for (int nt = 0; nt < 4; nt++) acc[mt][nt] = zero;

    pf(0); pf(1);
    __syncthreads();
    for (int kb = 0; kb < 32; kb++) {
        if (kb == 31) wb_drain(); else wb_leave4();
        if (kb + 2 < 32) pf(kb + 2);
        int sA = (kb % 3) * 8192, sB = 24576 + (kb % 3) * 8192;
        bf16x8 af[4], bfv[4];
        for (int mt = 0; mt < 4; mt++) {
            int r = wm + mt * 16 + lrow;
            af[mt] = *(const bf16x8*)(smem + sA + r * 64 + (q4 ^ ((r >> 1) & 3)) * 16);
        }
        for (int nt = 0; nt < 4; nt++) {
            int r = wn + nt * 16 + lrow;
            bfv[nt] = *(const bf16x8*)(smem + sB + r * 64 + (q4 ^ ((r >> 1) & 3)) * 16);
        }
        for (int mt = 0; mt < 4; mt++)
            for (int nt = 0; nt < 4; nt++)
                acc[mt][nt] = __builtin_amdgcn_mfma_f32_16x16x32_bf16(
                    af[mt], bfv[nt], acc[mt][nt], 0, 0, 0);
    }
    __syncthreads();
    __bf16* T = (__bf16*)smem;     // row stride 136 elems (272 B)

    float oscale = (z == 0) ? 0.125f : 1.0f;
    int rowoff = q4 * 4;
    int b = bm >> 4;
    int s_base = (bm & 15) * 128;
    if (z < 2) {
        for (int mt = 0; mt < 4; mt++) {
            for (int nt = 0; nt < 4; nt++) {
                int n_local = wn + nt * 16 + lrow;
                int hl = n_local >> 6, d = n_local & 63;
                for (int reg = 0; reg < 4; reg++) {
                    int s_local = wm + mt * 16 + rowoff + reg;
                    int s = s_base + s_local;
                    int dp = (d & 7) | ((((d >> 3) ^ s) & 7) << 3);
                    T[s_local * 136 + hl * 64 + dp] = (__bf16)(acc[mt][nt][reg] * oscale);
                }
            }
        }
        __syncthreads();
        char* gq = (char*)(z == 0 ? qw : kw);
        for (int i = 0; i < 8; i++) {
            int id = tid + i * 256;
            int hl = id >> 10, r = (id >> 3) & 127, j = id & 7;
            float4 val = *(float4*)((char*)T + r * 272 + hl * 128 + j * 16);
            *(float4*)(gq + ((size_t)((b * 16 + bn * 2 + hl) * 2048) + s_base + r) * 128
                          + j * 16) = val;
        }
    } else {
        for (int mt = 0; mt < 4; mt++) {
            int s0 = wm + mt * 16 + rowoff;
            int seg = s0 >> 6, j0 = s0 & 63;
            for (int nt = 0; nt < 4; nt++) {
                int n_local = wn + nt * 16 + lrow;
                int d = n_local & 63;
                int hi = ((j0 >> 3) ^ d) & 7;
                bf16x4 pk;
                for (int reg = 0; reg < 4; reg++) pk[reg] = (__bf16)acc[mt][nt][reg];
                *(bf16x4*)&T[n_local * 136 + seg * 64 + hi * 8 + (j0 & 7)] = pk;
            }
        }
        __syncthreads();
        char* gv = (char*)vt;
        for (int i = 0; i < 8; i++) {
            int id = tid + i * 256;
            int nl = id >> 4, j = id & 15;
            int hl = nl >> 6, dv = nl & 63;
            float4 val = *(float4*)((char*)T + nl * 272 + j * 16);
            *(float4*)(gv + (((size_t)((b * 16 + bn * 2 + hl) * 64 + dv)) * 2048 + s_base) * 2
                          + j * 16) = val;
        }
    }
}

// ---------------- flash attention, round 10: QBLK=128 (amortize the chain) ---
// Six structures (r0-r9) all land at 106-116us with per-tile-step cost ~2000cy
// while issue is ~500cy: the per-tile latency chain (barrier sync, K ds_read,
// exp sequence, P LDS round-trip) is irreducible by reordering (r9's skew:
// correct but 116us). So AMORTIZE it: each wave owns 32 queries (two 16-row
// subtiles). Per kv-tile step the same K/V ds_reads + staging + barriers now
// feed 2x the MFMAs and 2x the queries; block count halves (512 = one full
// resident round at 2 blocks/CU, LDS 56KB). Pairing g=bx / 15-bx keeps every
// block at exactly 36 tile-steps. Sync skeleton is r9's proven-correct one:
// in-loop vmem stream = gl2lds stages ONLY (v_mask in LDS, staged once per
// block), r5's 2-slot 1-ahead schedule with vmcnt(4)-leave, full drain at the
// phase boundary (stores/degenerate loads must not leak into counted waits).
// Causal zeroing generalized: key_glob > query_glob on boundary tiles
// (uniform gate per subtile).
__global__ __launch_bounds__(256, 2) void attn_kernel(
    const __bf16* __restrict__ QW, const __bf16* __restrict__ KW,
    const __bf16* __restrict__ VT, const float* __restrict__ v_mask,
    const float* __restrict__ q_mask, float* __restrict__ out)
{
    // grid (8,64) = 512 blocks; XCD remap (assumes lin%8 round-robin): each
    // XCD owns 8 contiguous bh (its K/V set = 4MB ~= one L2).
    int lin = blockIdx.x + (blockIdx.y << 3);
    int xcd = lin & 7;
    int jj  = lin >> 3;
    int bh  = (xcd << 3) + (jj >> 3);
    int bx  = jj & 7;
    int b = bh >> 4, h = bh & 15;

    __shared__ __align__(16) char lds[57344];
    // K slots: lds + slot*8192          (2 x 8KB)
    // V slots: lds + 16384 + slot*8192  (2 x 8KB)
    // P:       lds + 32768 + wave*4096  (16KB: 2 subtiles x 2KB per wave)
    // vms:     lds + 49152              (8KB v_mask row for this b)
    char*  Pw  = lds + 32768;
    float* vms = (float*)(lds + 49152);

    int tid = threadIdx.x;
    int wave = tid >> 6, lane = tid & 63;
    int mloc = lane & 15, q4 = lane >> 4;
    int rowoff = q4 * 4, x7 = mloc & 7;
    char* Pme = Pw + wave * 4096;

    const char* Krow = (const char*)KW + (size_t)bh * 2048 * 128;
    const char* Vrow = (const char*)VT + (size_t)bh * 64 * 4096;
    const float* vmrow = v_mask + (size_t)b * 2048;

    int id0 = tid, id1 = tid + 256;

    auto stage = [&](int kb, int slot) {
        char* kd = lds + slot * 8192;
        char* vd = lds + 16384 + slot * 8192;
        gl2lds16(Krow + (size_t)(kb * 64 + (id0 >> 3)) * 128 + (id0 & 7) * 16,
                 kd + id0 * 16);
        gl2lds16(Krow + (size_t)(kb * 64 + (id1 >> 3)) * 128 + (id1 & 7) * 16,
                 kd + id1 * 16);
        gl2lds16(Vrow + (size_t)(id0 >> 3) * 4096 + (size_t)kb * 128 + (id0 & 7) * 16,
                 vd + id0 * 16);
        gl2lds16(Vrow + (size_t)(id1 >> 3) * 4096 + (size_t)kb * 128 + (id1 & 7) * 16,
                 vd + id1 * 16);
    };

    // v_mask row -> LDS once per block (shared by both phases; same b).
    gl2lds16((const char*)vmrow + id0 * 16, (char*)vms + id0 * 16);
    gl2lds16((const char*)vmrow + 4096 + id0 * 16, (char*)vms + 4096 + id0 * 16);

    f32x4 zero = {0.f, 0.f, 0.f, 0.f};

    for (int p = 0; p < 2; p++) {
        int g = p ? (15 - bx) : bx;      // q-block of 128 queries
        int jmax = 2 * g + 1;            // kv tiles 0..jmax
        const char* Qrow = (const char*)QW +
                           ((size_t)bh * 2048 + g * 128 + wave * 32) * 128;
        bf16x8 qfr[2][2];                // [subtile][kc]
        for (int s = 0; s < 2; s++)
            for (int kc = 0; kc < 2; kc++)
                qfr[s][kc] = *(const bf16x8*)(Qrow + (s * 16 + mloc) * 128 +
                                              (((kc * 4 + q4) ^ x7) << 4));

        stage(0, 0);

        f32x4 o_acc[2][4];
        for (int s = 0; s < 2; s++)
            for (int nt = 0; nt < 4; nt++) o_acc[s][nt] = zero;
        float lt[2] = {0.f, 0.f};

        for (int j = 0; j <= jmax; j++) {
            int slot = j & 1;
            // In-loop vmem = stages only. Outstanding before wait:
            // [qfr(4)+vms(2)+... oldest, j==0 only] stage(j)[4] stage(j+1)[4]
            // -> vmcnt(4) leaves exactly stage(j+1); last iter drains all.
            if (j < jmax) {
                stage(j + 1, slot ^ 1);
                asm volatile("s_waitcnt vmcnt(4)\n\ts_barrier" ::: "memory");
            } else {
                asm volatile("s_waitcnt vmcnt(0)\n\ts_barrier" ::: "memory");
            }
            const char* Kls = lds + slot * 8192;
            const char* Vls = lds + 16384 + slot * 8192;

            // QK: K fragments shared across both q-subtiles (2x amortization)
            f32x4 sacc[2][4];
            for (int s = 0; s < 2; s++)
                for (int m = 0; m < 4; m++) sacc[s][m] = zero;
            for (int kc = 0; kc < 2; kc++) {
                bf16x8 kfr[4];
                for (int m = 0; m < 4; m++)
                    kfr[m] = *(const bf16x8*)(Kls + (m * 16 + mloc) * 128 +
                                              (((kc * 4 + q4) ^ x7) << 4));
                for (int m = 0; m < 4; m++) {
                    sacc[0][m] = __builtin_amdgcn_mfma_f32_16x16x32_bf16(
                        kfr[m], qfr[0][kc], sacc[0][m], 0, 0, 0);
                    sacc[1][m] = __builtin_amdgcn_mfma_f32_16x16x32_bf16(
                        kfr[m], qfr[1][kc], sacc[1][m], 0, 0, 0);
                }
            }

            // softmax + P pack, both subtiles
            for (int s = 0; s < 2; s++) {
                int qrow = g * 128 + wave * 32 + s * 16 + mloc;  // global q row
                bool clip = (64 * j + 63 > g * 128 + wave * 32 + s * 16);
                for (int m = 0; m < 4; m++) {
                    float4 vm4 = *(const float4*)&vms[j * 64 + m * 16 + rowoff];
                    float pen[4];
                    pen[0] = fmaf(1.0f - vm4.x, 1.0e9f, 12.0f);
                    pen[1] = fmaf(1.0f - vm4.y, 1.0e9f, 12.0f);
                    pen[2] = fmaf(1.0f - vm4.z, 1.0e9f, 12.0f);
                    pen[3] = fmaf(1.0f - vm4.w, 1.0e9f, 12.0f);
                    float pv[4];
                    for (int reg = 0; reg < 4; reg++)
                        pv[reg] = __expf(sacc[s][m][reg] - pen[reg]);
                    if (clip) {
                        int kb0 = 64 * j + m * 16 + rowoff;
                        for (int reg = 0; reg < 4; reg++)
                            if (kb0 + reg > qrow) pv[reg] = 0.f;
                    }
                    lt[s] += (pv[0] + pv[1]) + (pv[2] + pv[3]);
                    bf16x4 pk;
                    for (int reg = 0; reg < 4; reg++) pk[reg] = (__bf16)pv[reg];
                    *(bf16x4*)(Pme + s * 2048 + mloc * 128 +
                               (((m * 2 + (q4 >> 1)) ^ x7) << 4) + (q4 & 1) * 8) = pk;
                }
            }

            // PV: V fragments shared across both subtiles
            for (int kc = 0; kc < 2; kc++) {
                bf16x8 afr0 = *(const bf16x8*)(Pme + mloc * 128 +
                                               (((kc * 4 + q4) ^ x7) << 4));
                bf16x8 afr1 = *(const bf16x8*)(Pme + 2048 + mloc * 128 +
                                               (((kc * 4 + q4) ^ x7) << 4));
                bf16x8 vfr[4];
                for (int nt = 0; nt < 4; nt++)
                    vfr[nt] = *(const bf16x8*)(Vls + (nt * 16 + mloc) * 128 +
                                               (((kc * 4 + q4) ^ x7) << 4));
                for (int nt = 0; nt < 4; nt++) {
                    o_acc[0][nt] = __builtin_amdgcn_mfma_f32_16x16x32_bf16(
                        afr0, vfr[nt], o_acc[0][nt], 0, 0, 0);
                    o_acc[1][nt] = __builtin_amdgcn_mfma_f32_16x16x32_bf16(
                        afr1, vfr[nt], o_acc[1][nt], 0, 0, 0);
                }
            }

            // raw barrier: all waves' ds_reads of the opposite slot were
            // consumed by MFMAs above (lgkm-waited) before this point; next
            // iter's stage may then overwrite it.
            asm volatile("s_barrier" ::: "memory");
        }

        // l: sum over q4 key-groups
        for (int s = 0; s < 2; s++) {
            lt[s] += __shfl_xor(lt[s], 16);
            lt[s] += __shfl_xor(lt[s], 32);
        }

        // degenerate queries (entire causal window masked): uniform softmax
        // over {window} U {unmasked future}. Wave-local indicator pass (rare).
        if (__any((lt[0] == 0.0f) || (lt[1] == 0.0f))) {
            float l2[2] = {0.f, 0.f};
            for (int kb2 = 0; kb2 < 32; kb2++) {
                bf16x8 vfr[4][2];
                for (int nt = 0; nt < 4; nt++)
                    for (int kc = 0; kc < 2; kc++)
                        vfr[nt][kc] = *(const bf16x8*)(Vrow +
                            (size_t)(nt * 16 + mloc) * 4096 +
                            kb2 * 128 + (((kc * 4 + q4) ^ x7) << 4));
                for (int kc = 0; kc < 2; kc++) {
                    const float* vmp = &vms[kb2 * 64 + kc * 32 + q4 * 8];
                    float4 va = *(const float4*)vmp;
                    float4 vb4 = *(const float4*)(vmp + 4);
                    float vmj[8] = {va.x, va.y, va.z, va.w,
                                    vb4.x, vb4.y, vb4.z, vb4.w};
                    int kg0 = kb2 * 64 + kc * 32 + q4 * 8;
                    for (int s = 0; s < 2; s++) {
                        bool degrow = (lt[s] == 0.0f);
                        int qrow = g * 128 + wave * 32 + s * 16 + mloc;
                        bf16x8 af;
                        float cnt = 0.f;
                        for (int jx = 0; jx < 8; jx++) {
                            float ind = degrow ? ((kg0 + jx <= qrow) ? 1.0f : vmj[jx])
                                               : 0.0f;
                            af[jx] = (__bf16)ind;
                            cnt += ind;
                        }
                        l2[s] += cnt;
                        for (int nt = 0; nt < 4; nt++)
                            o_acc[s][nt] = __builtin_amdgcn_mfma_f32_16x16x32_bf16(
                                af, vfr[nt][kc], o_acc[s][nt], 0, 0, 0);
                    }
                }
            }
            for (int s = 0; s < 2; s++) {
                l2[s] += __shfl_xor(l2[s], 16);
                l2[s] += __shfl_xor(l2[s], 32);
                if (lt[s] == 0.0f) lt[s] = l2[s];
            }
        }

        // epilogue: direct scaled store per subtile
        for (int s = 0; s < 2; s++) {
            int q0 = g * 128 + wave * 32 + s * 16 + rowoff;
            float sc[4];
            for (int reg = 0; reg < 4; reg++) {
                float lq = __shfl(lt[s], rowoff + reg);
                sc[reg] = q_mask[b * 2048 + q0 + reg] / lq;
            }
            for (int nt = 0; nt < 4; nt++)
                for (int reg = 0; reg < 4; reg++)
                    out[((size_t)(b * 2048 + q0 + reg)) * 1024 +
                        h * 64 + nt * 16 + mloc] = o_acc[s][nt][reg] * sc[reg];
        }

        // PHASE BOUNDARY: full drain. Stores and degenerate-pass loads count
        // on vmcnt -- they must not leak into the next phase's counted waits.
        asm volatile("s_waitcnt vmcnt(0) lgkmcnt(0)\n\ts_barrier" ::: "memory");
    }
}

// ---------------- launch ------------------------------------------------------
extern "C" void kernel_launch(void* const* d_in, const int* in_sizes, int n_in,
                              void* d_out, int out_size, void* d_ws, size_t ws_size,
                              hipStream_t stream)
{
    const float* q      = (const float*)d_in[0];
    const float* k      = (const float*)d_in[1];
    const float* v      = (const float*)d_in[2];
    const float* v_mask = (const float*)d_in[3];
    const float* q_mask = (const float*)d_in[4];
    const float* Wq     = (const float*)d_in[5];
    const float* Wk     = (const float*)d_in[6];
    const float* Wv     = (const float*)d_in[7];
    float* out = (float*)d_out;

    __bf16* Abf = (__bf16*)d_ws;                 // 3 x 8192 x 1024
    __bf16* Wt  = Abf + (size_t)3 * 8388608;     // 3 x 1024 x 1024
    __bf16* qw  = Wt + (size_t)3 * 1048576;      // [B*H][S][64] (x0.125)
    __bf16* kw  = qw + (size_t)8388608;
    __bf16* vt  = kw + (size_t)8388608;          // [B*H][64][S]

    cast_swizzle_kernel<<<12288, 256, 0, stream>>>(q, k, v, Abf);
    transpose_cast_kernel<<<dim3(32, 32, 3), 256, 0, stream>>>(Wq, Wk, Wv, Wt);
    proj_gemm_kernel<<<dim3(64, 8, 3), 256, 0, stream>>>(Abf, Wt, qw, kw, vt);
    attn_kernel<<<dim3(8, 64), 256, 0, stream>>>(qw, kw, vt, v_mask, q_mask, out);
}